// Round 6
// baseline (37.293 us; speedup 1.0000x reference)
//
#include <hip/hip_runtime.h>

#define S7 7
#define NCELL 49            // S*S
#define CH 30
#define IMG_F (CH * NCELL)  // 1470 floats per image
#define K_IMG 2             // images per LDS tile; 2*1470 floats = 735 float4 per tensor
#define BLK 512             // 8 waves/block; 23.5 KB LDS -> 4 blocks/CU -> 32 waves/CU (100%)
#define NF4 (K_IMG * IMG_F / 4)  // 735 float4 per tensor per tile
#define GRID 1024           // persistent: 4 blocks/CU * 256 CU

typedef __attribute__((address_space(1))) const void global_cvoid;
typedef __attribute__((address_space(3))) void lds_void;

__global__ __launch_bounds__(BLK) void yolo_loss_stage1(
    const float4* __restrict__ pred4,
    const float4* __restrict__ lab4,
    float* __restrict__ partials,
    int npairs)
{
    __shared__ float4 sp4[NF4];
    __shared__ float4 sl4[NF4];
    const float* sp = (const float*)sp4;
    const float* sl = (const float*)sl4;

    const int tid = threadIdx.x;
    float contrib = 0.0f;

    // persistent grid-stride over image pairs (npairs = B/2 = 8192, grid = 1024 -> 8 iters)
    for (int pair = blockIdx.x; pair < npairs; pair += gridDim.x) {
        // ---- stage: async global->LDS, 16B/lane, linear dest (gl_lds-compatible) ----
        const size_t g4base = (size_t)pair * NF4;
        for (int i = tid; i < NF4; i += BLK) {
            __builtin_amdgcn_global_load_lds(
                (global_cvoid*)(pred4 + g4base + i),
                (lds_void*)(&sp4[i]), 16, 0, 0);
            __builtin_amdgcn_global_load_lds(
                (global_cvoid*)(lab4 + g4base + i),
                (lds_void*)(&sl4[i]), 16, 0, 0);
        }
        __syncthreads();   // drains vmcnt; LDS tile ready

        // ---- compute: one thread per cell (98 of 512), accumulate locally ----
        if (tid < K_IMG * NCELL) {
            const int img  = tid / NCELL;
            const int cell = tid - img * NCELL;
            const float* __restrict__ pb = sp + img * IMG_F + cell;
            const float* __restrict__ lb = sl + img * IMG_F + cell;

            float p[10], l[10];
            #pragma unroll
            for (int c = 0; c < 10; ++c) {
                p[c] = pb[c * NCELL];
                l[c] = lb[c * NCELL];
            }
            float cls = 0.0f;
            #pragma unroll
            for (int c = 10; c < CH; ++c) {
                float d = pb[c * NCELL] - lb[c * NCELL];
                cls += d * d;
            }

            const int   row = cell / S7;
            const float mi = (float)row;
            const float nj = (float)(cell - row * S7);
            const float invS = 1.0f / 7.0f;

            float ax1, ay1, ax2, ay2;
            {
                float cx = (p[0] + mi) * invS, cy = (p[1] + nj) * invS;
                ax1 = cx - 0.5f * p[2]; ay1 = cy - 0.5f * p[3];
                ax2 = cx + 0.5f * p[2]; ay2 = cy + 0.5f * p[3];
            }
            float bx1, by1, bx2, by2;
            {
                float cx = (p[5] + mi) * invS, cy = (p[6] + nj) * invS;
                bx1 = cx - 0.5f * p[7]; by1 = cy - 0.5f * p[8];
                bx2 = cx + 0.5f * p[7]; by2 = cy + 0.5f * p[8];
            }
            float gx1, gy1, gx2, gy2;
            {
                float cx = (l[0] + mi) * invS, cy = (l[1] + nj) * invS;
                gx1 = cx - 0.5f * l[2]; gy1 = cy - 0.5f * l[3];
                gx2 = cx + 0.5f * l[2]; gy2 = cy + 0.5f * l[3];
            }

            float iou1, iou2;
            {
                float ix1 = fmaxf(ax1, gx1), iy1 = fmaxf(ay1, gy1);
                float ix2 = fminf(ax2, gx2), iy2 = fminf(ay2, gy2);
                float inter = fmaxf(ix2 - ix1, 0.0f) * fmaxf(iy2 - iy1, 0.0f);
                float a1 = (ax2 - ax1) * (ay2 - ay1);
                float a2 = (gx2 - gx1) * (gy2 - gy1);
                float denom = a1 + a2 - inter;
                iou1 = (inter > 0.0f) ? inter / denom : 0.0f;
            }
            {
                float ix1 = fmaxf(bx1, gx1), iy1 = fmaxf(by1, gy1);
                float ix2 = fminf(bx2, gx2), iy2 = fminf(by2, gy2);
                float inter = fmaxf(ix2 - ix1, 0.0f) * fmaxf(iy2 - iy1, 0.0f);
                float a1 = (bx2 - bx1) * (by2 - by1);
                float a2 = (gx2 - gx1) * (gy2 - gy1);
                float denom = a1 + a2 - inter;
                iou2 = (inter > 0.0f) ? inter / denom : 0.0f;
            }

            const bool resp1 = (iou1 >= iou2);

            float d0 = p[0] - l[0], d1 = p[1] - l[1];
            float s2 = __builtin_sqrtf(p[2]) - __builtin_sqrtf(l[2]);
            float s3 = __builtin_sqrtf(p[3]) - __builtin_sqrtf(l[3]);
            float coor1 = 5.0f * (d0 * d0 + d1 * d1 + s2 * s2 + s3 * s3);

            float e0 = p[5] - l[5], e1 = p[6] - l[6];
            float t2 = __builtin_sqrtf(p[7]) - __builtin_sqrtf(l[7]);
            float t3 = __builtin_sqrtf(p[8]) - __builtin_sqrtf(l[8]);
            float coor2 = 5.0f * (e0 * e0 + e1 * e1 + t2 * t2 + t3 * t3);

            float o1 = p[4] - iou1; o1 *= o1;
            float o2 = p[9] - iou2; o2 *= o2;

            float coor       = resp1 ? coor1 : coor2;
            float obj_conf   = resp1 ? o1 : o2;
            float noobj_resp = 0.5f * (resp1 ? o2 : o1);
            float noobj_cell = 0.5f * (p[4] * p[4] + p[9] * p[9]);

            const bool obj = (l[4] == 1.0f);
            contrib += obj ? (coor + obj_conf + noobj_resp + cls) : noobj_cell;
        }
        __syncthreads();   // protect LDS before next tile overwrites
    }

    // ---- block reduction: wave shuffle -> LDS -> one partial store per block ----
    #pragma unroll
    for (int off = 32; off > 0; off >>= 1)
        contrib += __shfl_down(contrib, off, 64);

    __shared__ float wsum[BLK / 64];
    const int lane = tid & 63;
    const int wid  = tid >> 6;
    if (lane == 0) wsum[wid] = contrib;
    __syncthreads();
    if (tid == 0) {
        float bs = 0.0f;
        #pragma unroll
        for (int w = 0; w < BLK / 64; ++w) bs += wsum[w];
        partials[blockIdx.x] = bs;
    }
}

__global__ __launch_bounds__(1024) void yolo_loss_stage2(
    const float* __restrict__ partials,
    float* __restrict__ out,
    int nparts, float inv_B)
{
    float s = (threadIdx.x < nparts) ? partials[threadIdx.x] : 0.0f;

    #pragma unroll
    for (int off = 32; off > 0; off >>= 1)
        s += __shfl_down(s, off, 64);

    __shared__ float wsum[16];
    const int lane = threadIdx.x & 63;
    const int wid  = threadIdx.x >> 6;
    if (lane == 0) wsum[wid] = s;
    __syncthreads();
    if (threadIdx.x == 0) {
        float bs = 0.0f;
        #pragma unroll
        for (int w = 0; w < 16; ++w) bs += wsum[w];
        out[0] = bs * inv_B;
    }
}

extern "C" void kernel_launch(void* const* d_in, const int* in_sizes, int n_in,
                              void* d_out, int out_size, void* d_ws, size_t ws_size,
                              hipStream_t stream) {
    const float4* pred4 = (const float4*)d_in[0];
    const float4* lab4  = (const float4*)d_in[1];
    float* out = (float*)d_out;
    float* partials = (float*)d_ws;

    const int B = in_sizes[0] / IMG_F;     // 16384
    const int npairs = B / K_IMG;          // 8192
    const int grid = (npairs < GRID) ? npairs : GRID;   // 1024 persistent blocks

    yolo_loss_stage1<<<grid, BLK, 0, stream>>>(pred4, lab4, partials, npairs);
    yolo_loss_stage2<<<1, 1024, 0, stream>>>(partials, out, grid, 1.0f / (float)B);
}